// Round 1
// 1002.941 us; speedup vs baseline: 1.4087x; 1.4087x over previous
//
#include <hip/hip_runtime.h>
#include <stdint.h>

// Problem constants (B=2, S=8192, H=1024, F=2048, E=8, K=2)
#define T_TOK 16384
#define H_DIM 1024
#define F_DIM 2048
#define E_NUM 8
#define N_SLOT 32768           // T_TOK * 2
#define CAP 5120               // ceil(1.25 * 32768 / 8), divisible by 256
#define EGROUP 3               // experts per pipeline group (hbuf sized for this)

typedef __attribute__((ext_vector_type(8))) short bf16x8;   // 8 bf16 = 4 VGPRs
typedef __attribute__((ext_vector_type(4))) float f32x4;    // MFMA accumulator

__device__ __forceinline__ unsigned short f2bf(float f) {
  unsigned int x = __float_as_uint(f);
  x += 0x7fffu + ((x >> 16) & 1u);       // round-to-nearest-even
  return (unsigned short)(x >> 16);
}
__device__ __forceinline__ float bf2f(unsigned short u) {
  return __uint_as_float(((unsigned int)u) << 16);
}

// raw workgroup barrier, NO vmcnt/lgkm drain (the whole point vs __syncthreads):
// empty memory-clobber asm pins compiler-level ordering of LDS ops around it.
__device__ __forceinline__ void bar_sync() {
  asm volatile("" ::: "memory");
  __builtin_amdgcn_s_barrier();
  asm volatile("" ::: "memory");
}

// ---------------- fallback: ws too small -> zero out, report ws_size in aux ----------------
__global__ void fallback_kernel(float* out, int out_size, float wsval) {
  size_t i = (size_t)blockIdx.x * blockDim.x + threadIdx.x;
  size_t stride = (size_t)gridDim.x * blockDim.x;
  for (size_t k = i; k < (size_t)out_size; k += stride)
    out[k] = (k == (size_t)out_size - 1) ? wsval : 0.f;
}

// ---------------- zero control block ----------------
__global__ void zero_ctrl_kernel(float* imp, int* counts, int* order) {
  int i = threadIdx.x;
  if (i < E_NUM) { imp[i] = 0.f; counts[i] = 0; order[i] = 0; }
}

// ---- transpose + f32->bf16 convert: src [E][R][C] f32 -> dst [E][C][R] bf16 ----
__global__ __launch_bounds__(256) void transpose_kernel(
    const float* __restrict__ src, unsigned short* __restrict__ dst, int R, int C) {
  __shared__ float tile[32][33];
  int e = blockIdx.z;
  int c0 = blockIdx.x * 32, r0 = blockIdx.y * 32;
  int tx = threadIdx.x & 31, ty = threadIdx.x >> 5;
  const float* s = src + ((size_t)e * R + r0) * C + c0;
#pragma unroll
  for (int k = 0; k < 4; ++k) tile[ty + 8 * k][tx] = s[(size_t)(ty + 8 * k) * C + tx];
  __syncthreads();
  unsigned short* d = dst + ((size_t)e * C + c0) * R + r0;
#pragma unroll
  for (int k = 0; k < 4; ++k) d[(size_t)(ty + 8 * k) * R + tx] = f2bf(tile[tx][ty + 8 * k]);
}

// ---------------- router: fp64 logits/softmax/top-2 (tie-flip safety), importance/load ----------------
__global__ __launch_bounds__(256) void router_kernel(
    const float* __restrict__ x, const float* __restrict__ Wr,
    int* __restrict__ top_idx, float* __restrict__ top_w,
    float* __restrict__ importance, int* __restrict__ counts) {
  __shared__ float s_imp[E_NUM];
  __shared__ int s_cnt[E_NUM];
  int tid = threadIdx.x;
  if (tid < E_NUM) { s_imp[tid] = 0.f; s_cnt[tid] = 0; }
  __syncthreads();
  int wave = tid >> 6, lane = tid & 63;
  int t = blockIdx.x * 4 + wave;           // one wave per token
  double acc[E_NUM];
#pragma unroll
  for (int e = 0; e < E_NUM; ++e) acc[e] = 0.0;
  const float* xt = x + (size_t)t * H_DIM;
#pragma unroll 2
  for (int i = 0; i < H_DIM / 64; ++i) {
    int h = i * 64 + lane;
    double xv = (double)xt[h];
    const float4* wr = (const float4*)(Wr + h * E_NUM);
    float4 w0 = wr[0], w1 = wr[1];
    acc[0] += xv * (double)w0.x; acc[1] += xv * (double)w0.y;
    acc[2] += xv * (double)w0.z; acc[3] += xv * (double)w0.w;
    acc[4] += xv * (double)w1.x; acc[5] += xv * (double)w1.y;
    acc[6] += xv * (double)w1.z; acc[7] += xv * (double)w1.w;
  }
#pragma unroll
  for (int e = 0; e < E_NUM; ++e)
    for (int off = 32; off; off >>= 1) acc[e] += __shfl_xor(acc[e], off, 64);
  if (lane == 0) {
    double mx = acc[0];
#pragma unroll
    for (int e = 1; e < E_NUM; ++e) mx = acc[e] > mx ? acc[e] : mx;
    double p[E_NUM]; double s = 0.0;
#pragma unroll
    for (int e = 0; e < E_NUM; ++e) { p[e] = exp(acc[e] - mx); s += p[e]; }
    double inv = 1.0 / s;
    // top-2 (ties -> lower index, matching jax.lax.top_k)
    int i0 = 0; double p0 = p[0];
#pragma unroll
    for (int e = 1; e < E_NUM; ++e) if (p[e] > p0) { p0 = p[e]; i0 = e; }
    int i1 = -1; double p1 = -1.0;
#pragma unroll
    for (int e = 0; e < E_NUM; ++e) if (e != i0 && p[e] > p1) { p1 = p[e]; i1 = e; }
    double wsum = p0 + p1;
    top_idx[2 * t] = i0; top_idx[2 * t + 1] = i1;
    top_w[2 * t] = (float)(p0 / wsum);
    top_w[2 * t + 1] = (float)(p1 / wsum);
#pragma unroll
    for (int e = 0; e < E_NUM; ++e) atomicAdd(&s_imp[e], (float)(p[e] * inv));
    atomicAdd(&s_cnt[i0], 1); atomicAdd(&s_cnt[i1], 1);
  }
  __syncthreads();
  if (tid < E_NUM) { atomicAdd(&importance[tid], s_imp[tid]); atomicAdd(&counts[tid], s_cnt[tid]); }
}

// ---------------- aux loss ----------------
__global__ void aux_kernel(const float* __restrict__ importance, const int* __restrict__ counts,
                           float* __restrict__ aux_out) {
  if (threadIdx.x == 0) {
    float s = 0.f;
    for (int e = 0; e < E_NUM; ++e) s += importance[e] * (float)counts[e];
    *aux_out = (float)E_NUM * s / (float)N_SLOT;
  }
}

// ---------------- per-slot position assignment ----------------
__global__ __launch_bounds__(256) void assign_pos_kernel(
    const int* __restrict__ top_idx, const float* __restrict__ top_w,
    const int* __restrict__ counts, int* __restrict__ order, int* __restrict__ pos) {
  int i = blockIdx.x * 256 + threadIdx.x;
  if (i >= N_SLOT) return;
  int e = top_idx[i];
  int c = counts[e];
  if (c <= CAP) {
    pos[i] = atomicAdd(&order[e], 1);
  } else {
    float p = top_w[i]; int r = 0;
    for (int j = 0; j < N_SLOT; ++j) {
      if (top_idx[j] == e) {
        float q = top_w[j];
        r += (q > p) || (q == p && j < i);
      }
    }
    pos[i] = (r < CAP) ? r : -1;   // dropped
  }
}

// ---------------- dispatch: x[token] -> x_disp[e][pos] (bf16) ----------------
__global__ __launch_bounds__(256) void dispatch_kernel(
    const float* __restrict__ x, const int* __restrict__ top_idx,
    const int* __restrict__ pos, unsigned short* __restrict__ xd) {
  int s = blockIdx.x;
  int p = pos[s];
  if (p < 0) return;
  int e = top_idx[s];
  int t = s >> 1;
  float4 v = ((const float4*)(x + (size_t)t * H_DIM))[threadIdx.x];
  unsigned short* d = xd + ((size_t)e * CAP + p) * H_DIM + threadIdx.x * 4;
  *(ushort4*)d = make_ushort4(f2bf(v.x), f2bf(v.y), f2bf(v.z), f2bf(v.w));
}

// ---------------- GEMM staging: ROWSx64 bf16 tile via global_load_lds ----------------
// LDS row m chunk q (16B chunks) holds global chunk q ^ (m&7): 128B rows would be a
// 16-way bank conflict on ds_read_b128; the xor spreads the 16 rows of a quad-group
// over 8 chunk slots -> 2-way (free, m136). LDS dest stays linear (wave-uniform base
// + lane*16B contract); the global SOURCE is pre-swizzled (both-sides rule, m104).
template<int NCHUNK>
__device__ __forceinline__ void stage64(const unsigned short* __restrict__ g,
                                        unsigned short* s, int ldg, int tid) {
#pragma unroll
  for (int j = 0; j < NCHUNK / 512; ++j) {
    int c = j * 512 + tid;
    int m = c >> 3;
    int kc = (c & 7) ^ (m & 7);
    const unsigned short* gp = g + (size_t)m * ldg + kc * 8;
    __builtin_amdgcn_global_load_lds((const __attribute__((address_space(1))) void*)gp,
                                     (__attribute__((address_space(3))) void*)(s + (size_t)c * 8),
                                     16, 0, 0);
  }
}

// per-K-tile (BK=64) compute for gateup: per-wave 64x64, dual accumulators
__device__ __forceinline__ void gu_compute(const unsigned short* a, const unsigned short* bg,
                                           const unsigned short* bu, int wm, int wn, int lr,
                                           int quad, f32x4 (&accg)[4][4], f32x4 (&accu)[4][4]) {
#pragma unroll
  for (int kh = 0; kh < 2; ++kh) {
    int kq = kh * 4 + quad;
    bf16x8 af[4], gf[4], uf[4];
#pragma unroll
    for (int i = 0; i < 4; ++i) {
      int m = wm + i * 16 + lr;
      af[i] = *(const bf16x8*)&a[m * 64 + ((kq ^ (m & 7)) << 3)];
    }
#pragma unroll
    for (int j = 0; j < 4; ++j) {
      int n = wn + j * 16 + lr;
      int off = n * 64 + ((kq ^ (n & 7)) << 3);
      gf[j] = *(const bf16x8*)&bg[off];
      uf[j] = *(const bf16x8*)&bu[off];
    }
#pragma unroll
    for (int i = 0; i < 4; ++i)
#pragma unroll
      for (int j = 0; j < 4; ++j) {
        accg[i][j] = __builtin_amdgcn_mfma_f32_16x16x32_bf16(af[i], gf[j], accg[i][j], 0, 0, 0);
        accu[i][j] = __builtin_amdgcn_mfma_f32_16x16x32_bf16(af[i], uf[j], accu[i][j], 0, 0, 0);
      }
  }
}

// ---------------- fused gate/up GEMM + SiLU: h = silu(X@Wg) * (X@Wu) ----------------
// 256x128 tile, BK=64, 8 waves (4M x 2N, per-wave 64x64), double-buffered LDS (128 KB).
// Main loop: issue next tile's 8 global_load_lds -> vmcnt(8) (current landed, next in
// flight) -> raw barrier -> MFMA -> raw barrier. No vmcnt(0)/lgkmcnt(0) drain until the
// peeled last tile (T4, counted vmcnt — the m97-structure killer was the full drain).
__global__ __launch_bounds__(512, 2) void gateup_kernel(
    const unsigned short* __restrict__ xd, const unsigned short* __restrict__ wgT,
    const unsigned short* __restrict__ wuT, const int* __restrict__ counts,
    unsigned short* __restrict__ hbuf, int e0) {
  int ez = blockIdx.z;                    // local expert index within group
  int e = e0 + ez;                        // global expert
  int rows = counts[e]; rows = rows > CAP ? CAP : rows;
  int tm = blockIdx.y * 256;
  if (tm >= rows) return;                 // block-uniform early exit (before any barrier)
  int tn = blockIdx.x * 128;
  __shared__ __align__(16) unsigned short sA[2][256 * 64];   // 2 x 32 KB
  __shared__ __align__(16) unsigned short sBg[2][128 * 64];  // 2 x 16 KB
  __shared__ __align__(16) unsigned short sBu[2][128 * 64];  // 2 x 16 KB
  int tid = threadIdx.x;
  int lane = tid & 63, wave = tid >> 6;
  int quad = lane >> 4, lr = lane & 15;
  int wm = (wave >> 1) * 64, wn = (wave & 1) * 64;
  const unsigned short* A  = xd  + ((size_t)e * CAP + tm) * H_DIM;
  const unsigned short* Bg = wgT + ((size_t)e * F_DIM + tn) * H_DIM;
  const unsigned short* Bu = wuT + ((size_t)e * F_DIM + tn) * H_DIM;
  f32x4 accg[4][4], accu[4][4];
  f32x4 zero = {0.f, 0.f, 0.f, 0.f};
#pragma unroll
  for (int i = 0; i < 4; ++i)
#pragma unroll
    for (int j = 0; j < 4; ++j) { accg[i][j] = zero; accu[i][j] = zero; }

  // prologue: K-tile 0 into buffer 0 (8 loads in flight)
  stage64<2048>(A, sA[0], H_DIM, tid);
  stage64<1024>(Bg, sBg[0], H_DIM, tid);
  stage64<1024>(Bu, sBu[0], H_DIM, tid);
  const int NT = H_DIM / 64;  // 16
#pragma unroll 2
  for (int kt = 0; kt < NT - 1; ++kt) {
    int cur = kt & 1, nxt = cur ^ 1;
    // buf[nxt] was last read in compute(kt-1), fully drained before the trailing
    // barrier of the previous iteration -> safe to overwrite now.
    stage64<2048>(A + (kt + 1) * 64, sA[nxt], H_DIM, tid);
    stage64<1024>(Bg + (kt + 1) * 64, sBg[nxt], H_DIM, tid);
    stage64<1024>(Bu + (kt + 1) * 64, sBu[nxt], H_DIM, tid);
    asm volatile("s_waitcnt vmcnt(8)" ::: "memory");   // kt's 8 landed; kt+1's 8 in flight
    bar_sync();                                        // all waves' kt loads landed
    gu_compute(sA[cur], sBg[cur], sBu[cur], wm, wn, lr, quad, accg, accu);
    bar_sync();                                        // reads done before next overwrite
  }
  asm volatile("s_waitcnt vmcnt(0)" ::: "memory");     // only full drain: last tile
  bar_sync();
  gu_compute(sA[(NT - 1) & 1], sBg[(NT - 1) & 1], sBu[(NT - 1) & 1], wm, wn, lr, quad, accg, accu);

  // epilogue: silu(g)*u -> bf16  (C/D layout: row = quad*4+r, col = lr)
  unsigned short* hp = hbuf + ((size_t)ez * CAP + tm) * F_DIM + tn;
#pragma unroll
  for (int i = 0; i < 4; ++i)
#pragma unroll
    for (int j = 0; j < 4; ++j)
#pragma unroll
      for (int r = 0; r < 4; ++r) {
        int m = wm + i * 16 + quad * 4 + r;
        int n = wn + j * 16 + lr;
        float g = accg[i][j][r], u = accu[i][j][r];
        float hv = (g / (1.f + __expf(-g))) * u;
        hp[(size_t)m * F_DIM + n] = f2bf(hv);
      }
}

// per-K-tile compute for down: per-wave 128x64
__device__ __forceinline__ void dn_compute(const unsigned short* a, const unsigned short* b,
                                           int wm, int wn, int lr, int quad, f32x4 (&acc)[8][4]) {
#pragma unroll
  for (int kh = 0; kh < 2; ++kh) {
    int kq = kh * 4 + quad;
    bf16x8 af[8], bf[4];
#pragma unroll
    for (int i = 0; i < 8; ++i) {
      int m = wm + i * 16 + lr;
      af[i] = *(const bf16x8*)&a[m * 64 + ((kq ^ (m & 7)) << 3)];
    }
#pragma unroll
    for (int j = 0; j < 4; ++j) {
      int n = wn + j * 16 + lr;
      bf[j] = *(const bf16x8*)&b[n * 64 + ((kq ^ (n & 7)) << 3)];
    }
#pragma unroll
    for (int i = 0; i < 8; ++i)
#pragma unroll
      for (int j = 0; j < 4; ++j)
        acc[i][j] = __builtin_amdgcn_mfma_f32_16x16x32_bf16(af[i], bf[j], acc[i][j], 0, 0, 0);
  }
}

// ---------------- down GEMM: y = h @ W2 ----------------
// 256x256 tile, BK=64, 8 waves (2M x 4N, per-wave 128x64), same counted-vmcnt schedule.
__global__ __launch_bounds__(512, 2) void down_kernel(
    const unsigned short* __restrict__ hbuf, const unsigned short* __restrict__ w2T,
    const int* __restrict__ counts, unsigned short* __restrict__ ybuf, int e0) {
  int ez = blockIdx.z;
  int e = e0 + ez;
  int rows = counts[e]; rows = rows > CAP ? CAP : rows;
  int tm = blockIdx.y * 256;
  if (tm >= rows) return;
  int tn = blockIdx.x * 256;
  __shared__ __align__(16) unsigned short sA[2][256 * 64];   // 2 x 32 KB
  __shared__ __align__(16) unsigned short sB[2][256 * 64];   // 2 x 32 KB
  int tid = threadIdx.x;
  int lane = tid & 63, wave = tid >> 6;
  int quad = lane >> 4, lr = lane & 15;
  int wm = (wave >> 2) * 128, wn = (wave & 3) * 64;
  const unsigned short* A = hbuf + ((size_t)ez * CAP + tm) * F_DIM;
  const unsigned short* B = w2T + ((size_t)e * H_DIM + tn) * F_DIM;
  f32x4 acc[8][4];
  f32x4 zero = {0.f, 0.f, 0.f, 0.f};
#pragma unroll
  for (int i = 0; i < 8; ++i)
#pragma unroll
    for (int j = 0; j < 4; ++j) acc[i][j] = zero;

  stage64<2048>(A, sA[0], F_DIM, tid);
  stage64<2048>(B, sB[0], F_DIM, tid);
  const int NT = F_DIM / 64;  // 32
#pragma unroll 2
  for (int kt = 0; kt < NT - 1; ++kt) {
    int cur = kt & 1, nxt = cur ^ 1;
    stage64<2048>(A + (kt + 1) * 64, sA[nxt], F_DIM, tid);
    stage64<2048>(B + (kt + 1) * 64, sB[nxt], F_DIM, tid);
    asm volatile("s_waitcnt vmcnt(8)" ::: "memory");
    bar_sync();
    dn_compute(sA[cur], sB[cur], wm, wn, lr, quad, acc);
    bar_sync();
  }
  asm volatile("s_waitcnt vmcnt(0)" ::: "memory");
  bar_sync();
  dn_compute(sA[(NT - 1) & 1], sB[(NT - 1) & 1], wm, wn, lr, quad, acc);

  unsigned short* yp = ybuf + ((size_t)e * CAP + tm) * H_DIM + tn;
#pragma unroll
  for (int i = 0; i < 8; ++i)
#pragma unroll
    for (int j = 0; j < 4; ++j)
#pragma unroll
      for (int r = 0; r < 4; ++r) {
        int m = wm + i * 16 + quad * 4 + r;
        int n = wn + j * 16 + lr;
        yp[(size_t)m * H_DIM + n] = f2bf(acc[i][j][r]);
      }
}

// ---------------- combine: out[t] = sum_k w_k * y[e_k][pos_k] ----------------
__global__ __launch_bounds__(256) void combine_kernel(
    const unsigned short* __restrict__ ybuf, const int* __restrict__ top_idx,
    const int* __restrict__ pos, const float* __restrict__ top_w,
    float* __restrict__ out) {
  int t = blockIdx.x;
  int i0 = 2 * t, i1 = 2 * t + 1;
  int e0 = top_idx[i0], e1 = top_idx[i1];
  int p0 = pos[i0], p1 = pos[i1];
  float w0 = (p0 >= 0) ? top_w[i0] : 0.f;
  float w1 = (p1 >= 0) ? top_w[i1] : 0.f;
  size_t o0 = ((size_t)e0 * CAP + (p0 < 0 ? 0 : p0)) * H_DIM + threadIdx.x * 4;
  size_t o1 = ((size_t)e1 * CAP + (p1 < 0 ? 0 : p1)) * H_DIM + threadIdx.x * 4;
  ushort4 a = *(const ushort4*)(ybuf + o0);
  ushort4 b = *(const ushort4*)(ybuf + o1);
  float4 o;
  o.x = w0 * bf2f(a.x) + w1 * bf2f(b.x);
  o.y = w0 * bf2f(a.y) + w1 * bf2f(b.y);
  o.z = w0 * bf2f(a.z) + w1 * bf2f(b.z);
  o.w = w0 * bf2f(a.w) + w1 * bf2f(b.w);
  *(float4*)(out + (size_t)t * H_DIM + threadIdx.x * 4) = o;
}

extern "C" void kernel_launch(void* const* d_in, const int* in_sizes, int n_in,
                              void* d_out, int out_size, void* d_ws, size_t ws_size,
                              hipStream_t stream) {
  const float* x  = (const float*)d_in[0];   // [2,8192,1024]
  const float* Wr = (const float*)d_in[1];   // [1024,8]
  const float* Wg = (const float*)d_in[2];   // [8,1024,2048]
  const float* Wu = (const float*)d_in[3];   // [8,1024,2048]
  const float* W2 = (const float*)d_in[4];   // [8,2048,1024]
  float* out = (float*)d_out;                // [16M out] + [1 aux]

  // ---- workspace layout (grouped hbuf; peak 248.0 MB, ws_size = 256 MiB) ----
  const size_t SZ_W  = (size_t)E_NUM * F_DIM * H_DIM * 2;    // 33.55 MB per transposed weight
  const size_t SZ_XD = (size_t)E_NUM * CAP * H_DIM * 2;      // 83.89 MB
  const size_t SZ_HG = (size_t)EGROUP * CAP * F_DIM * 2;     // 62.91 MB (3-expert hbuf)
  const size_t NEED  = 524288 + 3 * SZ_W + SZ_XD + SZ_HG;    // 247.99 MB

  if (ws_size < NEED) {
    fallback_kernel<<<4096, 256, 0, stream>>>(out, out_size, (float)ws_size);
    return;
  }

  char* w = (char*)d_ws;
  float* importance = (float*)(w + 0);
  int* counts       = (int*)(w + 64);
  int* order        = (int*)(w + 128);
  int* top_idx      = (int*)(w + 1024);
  int* pos          = (int*)(w + 1024 + 131072);
  float* top_w      = (float*)(w + 1024 + 2 * 131072);
  size_t off = 524288;
  unsigned short* wgT  = (unsigned short*)(w + off); off += SZ_W;
  unsigned short* wuT  = (unsigned short*)(w + off); off += SZ_W;
  unsigned short* w2T  = (unsigned short*)(w + off); off += SZ_W;
  unsigned short* xd   = (unsigned short*)(w + off); off += SZ_XD;
  unsigned short* hbuf = (unsigned short*)(w + off); off += SZ_HG;
  unsigned short* ybuf = xd;    // aliases xd: down(e) runs after gateup(e) consumed xd[e]

  zero_ctrl_kernel<<<1, 64, 0, stream>>>(importance, counts, order);
  // weight transposes (src [E][R][C] f32 -> dst [E][C][R] bf16)
  transpose_kernel<<<dim3(F_DIM / 32, H_DIM / 32, E_NUM), 256, 0, stream>>>(Wg, wgT, H_DIM, F_DIM);
  transpose_kernel<<<dim3(F_DIM / 32, H_DIM / 32, E_NUM), 256, 0, stream>>>(Wu, wuT, H_DIM, F_DIM);
  transpose_kernel<<<dim3(H_DIM / 32, F_DIM / 32, E_NUM), 256, 0, stream>>>(W2, w2T, F_DIM, H_DIM);
  router_kernel<<<T_TOK / 4, 256, 0, stream>>>(x, Wr, top_idx, top_w, importance, counts);
  aux_kernel<<<1, 64, 0, stream>>>(importance, counts, out + (out_size - 1));
  assign_pos_kernel<<<N_SLOT / 256, 256, 0, stream>>>(top_idx, top_w, counts, order, pos);
  dispatch_kernel<<<N_SLOT, 256, 0, stream>>>(x, top_idx, pos, xd);
  // expert groups: hbuf holds <= EGROUP experts at a time
  for (int e0 = 0; e0 < E_NUM; e0 += EGROUP) {
    int ne = (E_NUM - e0) < EGROUP ? (E_NUM - e0) : EGROUP;
    gateup_kernel<<<dim3(F_DIM / 128, CAP / 256, ne), 512, 0, stream>>>(xd, wgT, wuT, counts, hbuf, e0);
    down_kernel<<<dim3(H_DIM / 256, CAP / 256, ne), 512, 0, stream>>>(hbuf, w2T, counts, ybuf, e0);
  }
  combine_kernel<<<T_TOK, 256, 0, stream>>>(ybuf, top_idx, pos, top_w, out);
}